// Round 15
// baseline (191.465 us; speedup 1.0000x reference)
//
#include <hip/hip_runtime.h>
#include <hip/hip_bf16.h>

#define NTOK 512
#define TJ 32
#define NHALF 8            // j-tiles per half-block (2 blocks per i)
#define EPSF 1e-5f

typedef __attribute__((ext_vector_type(4))) float f32x4;
typedef __attribute__((ext_vector_type(8))) short bf16x8;
typedef __attribute__((ext_vector_type(4))) short bf16x4;

struct HL { short hi; short lo; };

__device__ __forceinline__ short f2bf(float x) {
  __hip_bfloat16 h = __float2bfloat16(x);
  return *reinterpret_cast<short*>(&h);
}
__device__ __forceinline__ float bf2f(short s) {
  unsigned int u = ((unsigned int)(unsigned short)s) << 16;
  return __uint_as_float(u);
}
// RNE split x ~= hi + lo (~17 mantissa bits combined)
__device__ __forceinline__ HL splitbf(float x) {
  HL r;
  r.hi = f2bf(x);
  r.lo = f2bf(x - bf2f(r.hi));
  return r;
}

// R5's EXACT main-loop LDS (32000 B, maskf array included) -- 2 blocks/CU:
// two independent 8-wave barrier domains (R5-vs-R10: worth 18 us).
// R14's staging "improvements" (12B-stride f1 loads, per-thread mask loads)
// cost ~5 us and are reverted verbatim here.
struct __align__(16) SMemMain {
  float f0s[32*17];      // [j][f], stride 17
  float f1s[32*49];      // [j][c*3+x], stride 49
  float rhs[96];         // [j*3+x]
  float maskf[32];
  short rbfHL[32*40];    // [j][k]: k<16 hi, k>=16 lo; 80B row stride
  short Hh[128*40];      // [h][j] bf16 hi, stride 40
  short Hl[128*40];      // lo
};
union __align__(16) SMemU {
  SMemMain m;
  struct {               // epilogue region (disjoint lifetime, ~17.9 KB)
    float ACCs[128*33];
    float biasR[128];
    float tot[64];
    float rawbs[48], nrms[16];
  } e;
};

// ONE kernel, 1024 blocks (i = bid>>1, j-half = bid&1), 512 threads = 8 waves.
// Main loop = R5's verbatim 57us structure. Tail: in-block 2nd-layer
// contraction (linear in ACC -> 64 floats), direct per-thread atomicAdd to ws
// (coherent point -- no __threadfence, R9's 380us lesson), vmcnt(0)-ordered
// arrival counter; LAST arrival atomic-reads totals and runs LN. No spin.
// NEVER launch_bounds(x,8): reg wall proven R3+R11.
__global__ __launch_bounds__(512, 4) void tfn_fused(
    const float* __restrict__ f0,  const float* __restrict__ f1,
    const float* __restrict__ rbf, const float* __restrict__ rhat,
    const int*  __restrict__ mask,
    const float* __restrict__ w00a, const float* __restrict__ b00a,
    const float* __restrict__ w00b, const float* __restrict__ b00b,
    const float* __restrict__ w10a, const float* __restrict__ b10a,
    const float* __restrict__ w10b, const float* __restrict__ b10b,
    const float* __restrict__ w01a, const float* __restrict__ b01a,
    const float* __restrict__ w01b, const float* __restrict__ b01b,
    const float* __restrict__ w11a, const float* __restrict__ b11a,
    const float* __restrict__ w11b, const float* __restrict__ b11b,
    const float* __restrict__ g0, const float* __restrict__ be0,
    const float* __restrict__ g1, const float* __restrict__ be1,
    float* __restrict__ ws, int* __restrict__ cnt,
    float* __restrict__ out)
{
  __shared__ SMemU sm;
  __shared__ int lastflag;
  const int bid = blockIdx.x;
  const int i = bid >> 1;
  const int jbase = (bid & 1) * (NHALF * TJ);
  const int t = threadIdx.x;
  const int w = t >> 6;
  const int lane = t & 63;
  const int col = lane & 15;
  const int quad = lane >> 4;

  // ---- per-wave WA B-frags: bw1 = [Whi | Whi], bw2 = [Wlo | 0] ----
  bf16x8 bw1, bw2;
  float bav;
  {
    const int h = w*16 + col;
    const float* wa = (w < 2) ? (w00a + h*16) : (w < 4) ? (w10a + (h-32)*16)
                    : (w < 6) ? (w01a + (h-64)*16) : (w11a + (h-96)*16);
    bav = (w < 2) ? b00a[h] : (w < 4) ? b10a[h-32] : (w < 6) ? b01a[h-64] : b11a[h-96];
    #pragma unroll
    for (int e = 0; e < 8; ++e) {
      HL s = splitbf(wa[(quad & 1)*8 + e]);
      bw1[e] = s.hi;
      bw2[e] = (quad < 2) ? s.lo : (short)0;
    }
  }

  // ---- per-lane LHS constants (wave-uniform branch selectors) ----
  int fdiv = 0, xrem = 0, cidx = 0;
  if (w >= 2 && w < 5) { const int idx = (w-2)*16 + col; fdiv = idx/3; xrem = idx - 3*fdiv; }
  if (w >= 5) cidx = (w-5)*16 + col;
  const int hb = (w == 0) ? 0 : (w == 1) ? 2 : (w < 5) ? 4 : 6;

  // f1 staging index precompute (R5-verbatim)
  int f1q0, f1r0, f1q1, f1r1, f1q2, f1r2;
  { int a = t;        f1q0 = a/48; f1r0 = a - 48*f1q0; }
  { int a = t + 512;  f1q1 = a/48; f1r1 = a - 48*f1q1; }
  { int a = t + 1024; f1q2 = a/48; f1r2 = a - 48*f1q2; }
  const int jrow = t >> 4, jfeat = t & 15;

  // ---- prefetch tile 0 (R5-verbatim coalesced pattern) ----
  float pf_f0, pf_f1_0, pf_f1_1, pf_f1_2, pf_rh = 0.f, pf_rbf;
  int pf_mk = 0;
  {
    pf_f0   = f0[(jbase + jrow)*16 + jfeat];
    pf_f1_0 = f1[jbase*48 + t]; pf_f1_1 = f1[jbase*48 + t + 512]; pf_f1_2 = f1[jbase*48 + t + 1024];
    if (t < 96) pf_rh = rhat[((size_t)i*NTOK + jbase)*3 + t];
    if (t < 32) pf_mk = mask[(size_t)i*NTOK + jbase + t];
    pf_rbf  = rbf[((size_t)i*NTOK + jbase + jrow)*16 + jfeat];
  }

  f32x4 acc0 = {0.f,0.f,0.f,0.f}, acc1 = {0.f,0.f,0.f,0.f};
  float biasp = 0.f;
  const f32x4 zc = {0.f,0.f,0.f,0.f};

  for (int tile = 0; tile < NHALF; ++tile) {
    // ---- stage regs -> LDS ----
    sm.m.f0s[jrow*17 + jfeat] = pf_f0;
    sm.m.f1s[f1q0*49 + f1r0] = pf_f1_0;
    sm.m.f1s[f1q1*49 + f1r1] = pf_f1_1;
    sm.m.f1s[f1q2*49 + f1r2] = pf_f1_2;
    if (t < 96) sm.m.rhs[t] = pf_rh;
    if (t < 32) sm.m.maskf[t] = pf_mk ? 1.f : 0.f;
    { HL s = splitbf(pf_rbf);
      sm.m.rbfHL[jrow*40 + jfeat]      = s.hi;
      sm.m.rbfHL[jrow*40 + 16 + jfeat] = s.lo; }
    __syncthreads();   // staging visible

    // ---- prefetch tile+1 ----
    if (tile + 1 < NHALF) {
      const int j0 = jbase + (tile+1)*TJ;
      pf_f0   = f0[(j0 + jrow)*16 + jfeat];
      pf_f1_0 = f1[j0*48 + t]; pf_f1_1 = f1[j0*48 + t + 512]; pf_f1_2 = f1[j0*48 + t + 1024];
      if (t < 96) pf_rh = rhat[((size_t)i*NTOK + j0)*3 + t];
      if (t < 32) pf_mk = mask[(size_t)i*NTOK + j0 + t];
      pf_rbf  = rbf[((size_t)i*NTOK + j0 + jrow)*16 + jfeat];
    }

    // ---- phase A: H = silu(rbf @ WA^T + ba) ----
    {
      const bf16x8 a0 = *(const bf16x8*)&sm.m.rbfHL[col*40 + quad*8];
      const bf16x8 a1 = *(const bf16x8*)&sm.m.rbfHL[(16+col)*40 + quad*8];
      f32x4 d0 = __builtin_amdgcn_mfma_f32_16x16x32_bf16(a0, bw1, zc, 0, 0, 0);
      d0 = __builtin_amdgcn_mfma_f32_16x16x32_bf16(a0, bw2, d0, 0, 0, 0);
      f32x4 d1 = __builtin_amdgcn_mfma_f32_16x16x32_bf16(a1, bw1, zc, 0, 0, 0);
      d1 = __builtin_amdgcn_mfma_f32_16x16x32_bf16(a1, bw2, d1, 0, 0, 0);
      bf16x4 hv, lv;
      #pragma unroll
      for (int r = 0; r < 4; ++r) {
        float p = d0[r] + bav;
        float s = p * __builtin_amdgcn_rcpf(1.f + __expf(-p));
        HL e2 = splitbf(s); hv[r] = e2.hi; lv[r] = e2.lo;
      }
      *(bf16x4*)&sm.m.Hh[(w*16+col)*40 + quad*4] = hv;
      *(bf16x4*)&sm.m.Hl[(w*16+col)*40 + quad*4] = lv;
      #pragma unroll
      for (int r = 0; r < 4; ++r) {
        float p = d1[r] + bav;
        float s = p * __builtin_amdgcn_rcpf(1.f + __expf(-p));
        HL e2 = splitbf(s); hv[r] = e2.hi; lv[r] = e2.lo;
      }
      *(bf16x4*)&sm.m.Hh[(w*16+col)*40 + 16 + quad*4] = hv;
      *(bf16x4*)&sm.m.Hl[(w*16+col)*40 + 16 + quad*4] = lv;
    }

    // ---- LHS: per-lane phase-B A-frag (R5-verbatim, maskf in LDS) ----
    bf16x8 afh, afl;
    {
      const int jb = quad*8;
      float mkv[8];
      { const float4 mk0 = *(const float4*)&sm.m.maskf[jb];
        const float4 mk1 = *(const float4*)&sm.m.maskf[jb + 4];
        mkv[0]=mk0.x; mkv[1]=mk0.y; mkv[2]=mk0.z; mkv[3]=mk0.w;
        mkv[4]=mk1.x; mkv[5]=mk1.y; mkv[6]=mk1.z; mkv[7]=mk1.w; }
      float v[8];
      if (w == 0) {
        #pragma unroll
        for (int jj = 0; jj < 8; ++jj) v[jj] = mkv[jj] * sm.m.f0s[(jb+jj)*17 + col];
      } else if (w < 5) {
        float rwin[24];
        #pragma unroll
        for (int q4 = 0; q4 < 6; ++q4) {
          const float4 rr = *(const float4*)&sm.m.rhs[jb*3 + q4*4];
          rwin[q4*4+0]=rr.x; rwin[q4*4+1]=rr.y; rwin[q4*4+2]=rr.z; rwin[q4*4+3]=rr.w;
        }
        if (w == 1) {
          #pragma unroll
          for (int jj = 0; jj < 8; ++jj) {
            const float* fr = &sm.m.f1s[(jb+jj)*49 + col*3];
            v[jj] = mkv[jj] * (rwin[jj*3+0]*fr[0] + rwin[jj*3+1]*fr[1] + rwin[jj*3+2]*fr[2]);
          }
        } else {
          #pragma unroll
          for (int jj = 0; jj < 8; ++jj)
            v[jj] = mkv[jj] * sm.m.f0s[(jb+jj)*17 + fdiv] * rwin[jj*3 + xrem];
        }
      } else {
        #pragma unroll
        for (int jj = 0; jj < 8; ++jj) v[jj] = mkv[jj] * sm.m.f1s[(jb+jj)*49 + cidx];
      }
      #pragma unroll
      for (int jj = 0; jj < 8; ++jj) {
        biasp += v[jj];
        HL s = splitbf(v[jj]);
        afh[jj] = s.hi; afl[jj] = s.lo;
      }
    }
    __syncthreads();   // H visible; staging fully consumed

    // ---- phase B: ACC += L^T * H ----
    {
      const bf16x8 b0h = *(const bf16x8*)&sm.m.Hh[(hb*16+col)*40 + quad*8];
      const bf16x8 b0l = *(const bf16x8*)&sm.m.Hl[(hb*16+col)*40 + quad*8];
      const bf16x8 b1h = *(const bf16x8*)&sm.m.Hh[((hb+1)*16+col)*40 + quad*8];
      const bf16x8 b1l = *(const bf16x8*)&sm.m.Hl[((hb+1)*16+col)*40 + quad*8];
      acc0 = __builtin_amdgcn_mfma_f32_16x16x32_bf16(afl, b0h, acc0, 0, 0, 0);
      acc0 = __builtin_amdgcn_mfma_f32_16x16x32_bf16(afh, b0l, acc0, 0, 0, 0);
      acc0 = __builtin_amdgcn_mfma_f32_16x16x32_bf16(afh, b0h, acc0, 0, 0, 0);
      acc1 = __builtin_amdgcn_mfma_f32_16x16x32_bf16(afl, b1h, acc1, 0, 0, 0);
      acc1 = __builtin_amdgcn_mfma_f32_16x16x32_bf16(afh, b1l, acc1, 0, 0, 0);
      acc1 = __builtin_amdgcn_mfma_f32_16x16x32_bf16(afh, b1h, acc1, 0, 0, 0);
    }
  }

  __syncthreads();   // main LDS dead -> epilogue region live

  // ---- dump partial ACC + wave-reduced bias to LDS ----
  #pragma unroll
  for (int r = 0; r < 4; ++r) {
    sm.e.ACCs[(w*16 + quad*4 + r)*33 + col]      = acc0[r];
    sm.e.ACCs[(w*16 + quad*4 + r)*33 + 16 + col] = acc1[r];
  }
  biasp += __shfl_xor(biasp, 16);
  biasp += __shfl_xor(biasp, 32);
  if (lane < 16) sm.e.biasR[w*16 + col] = biasp;
  __syncthreads();

  // ---- partial 2nd-layer contraction (linear in ACC), 4-way d-split;
  //      each thread atomicAdds its single partial to ws (no part[] round) ----
  {
    const int tt = t & 127, g4 = t >> 7;   // g4 0..3
    float s = 0.f;
    int slot;
    if (tt < 16) {
      const int o = tt; slot = o;
      #pragma unroll
      for (int dd = 0; dd < 4; ++dd) {
        const int d = g4 + dd*4;
        const float* wrow = w00b + (d*16 + o)*32;
        float ss = 0.f;
        #pragma unroll
        for (int hh = 0; hh < 32; ++hh) ss += wrow[hh] * sm.e.ACCs[d*33 + hh];
        s += ss + b00b[d*16 + o] * sm.e.biasR[d];
      }
    } else if (tt < 32) {
      const int o = tt - 16; slot = o;
      #pragma unroll
      for (int dd = 0; dd < 4; ++dd) {
        const int c = g4 + dd*4, m = 16 + c;
        const float* wrow = w10b + (c*16 + o)*32;
        float ss = 0.f;
        #pragma unroll
        for (int hh = 0; hh < 32; ++hh) ss += wrow[hh] * sm.e.ACCs[m*33 + hh];
        s += ss + b10b[c*16 + o] * sm.e.biasR[m];
      }
    } else if (tt < 80) {
      const int idx = tt - 32, g = idx/3, x = idx - 3*g; slot = 16 + idx;
      #pragma unroll
      for (int dd = 0; dd < 4; ++dd) {
        const int f = g4 + dd*4, m = 32 + f*3 + x;
        const float* wrow = w01b + (f*16 + g)*32;
        float ss = 0.f;
        #pragma unroll
        for (int hh = 0; hh < 32; ++hh) ss += wrow[hh] * sm.e.ACCs[m*33 + hh];
        s += ss + b01b[f*16 + g] * sm.e.biasR[m];
      }
    } else {
      const int idx = tt - 80, g = idx/3, x = idx - 3*g; slot = 16 + idx;
      #pragma unroll
      for (int dd = 0; dd < 4; ++dd) {
        const int k = g4 + dd*4, m = 80 + k*3 + x;
        const float* wrow = w11b + (k*16 + g)*32;
        float ss = 0.f;
        #pragma unroll
        for (int hh = 0; hh < 32; ++hh) ss += wrow[hh] * sm.e.ACCs[m*33 + hh];
        s += ss + b11b[k*16 + g] * sm.e.biasR[m];
      }
    }
    atomicAdd(&ws[(size_t)i*64 + slot], s);
  }

  // ---- order data atomics, then count arrival (both at coherent point) ----
  asm volatile("s_waitcnt vmcnt(0)" ::: "memory");
  __syncthreads();
  if (t == 0) lastflag = atomicAdd(&cnt[i], 1);
  __syncthreads();
  if (lastflag == 0) return;   // first block done; frees CU slot

  // ================= LN epilogue (last-arriving block only) =================
  float* wsi = ws + (size_t)i * 64;
  if (t < 64) sm.e.tot[t] = atomicAdd(&wsi[t], 0.f);   // coherent reads
  __syncthreads();

  if (t < 16) {
    float vv = sm.e.tot[t];
    float mu = 0.f;
    #pragma unroll
    for (int k = 0; k < 16; ++k) mu += sm.e.tot[k];
    mu *= (1.f/16.f);
    float var = 0.f;
    #pragma unroll
    for (int k = 0; k < 16; ++k) { float d = sm.e.tot[k] - mu; var += d*d; }
    var *= (1.f/16.f);
    out[(size_t)i*16 + t] = (vv - mu) * rsqrtf(var + EPSF) * g0[t] + be0[t];
    const float r0v = sm.e.tot[16 + t*3 + 0];
    const float r1v = sm.e.tot[16 + t*3 + 1];
    const float r2v = sm.e.tot[16 + t*3 + 2];
    sm.e.rawbs[t*3+0] = r0v; sm.e.rawbs[t*3+1] = r1v; sm.e.rawbs[t*3+2] = r2v;
    sm.e.nrms[t] = fmaxf(sqrtf(r0v*r0v + r1v*r1v + r2v*r2v), 1e-8f);
  }
  __syncthreads();
  if (t < 16) {
    float mu = 0.f;
    #pragma unroll
    for (int k = 0; k < 16; ++k) mu += sm.e.nrms[k];
    mu *= (1.f/16.f);
    float var = 0.f;
    #pragma unroll
    for (int k = 0; k < 16; ++k) { float d = sm.e.nrms[k] - mu; var += d*d; }
    var *= (1.f/16.f);
    const float ln = (sm.e.nrms[t] - mu) * rsqrtf(var + EPSF) * g1[t] + be1[t];
    const float scale = ln / sm.e.nrms[t];
    const size_t base = (size_t)NTOK*16 + (size_t)i*48 + t*3;
    out[base+0] = sm.e.rawbs[t*3+0] * scale;
    out[base+1] = sm.e.rawbs[t*3+1] * scale;
    out[base+2] = sm.e.rawbs[t*3+2] * scale;
  }
}

extern "C" void kernel_launch(void* const* d_in, const int* in_sizes, int n_in,
                              void* d_out, int out_size, void* d_ws, size_t ws_size,
                              hipStream_t stream) {
  int idx_f0 = -1, idx_f1 = -1, idx_rbf = -1, idx_rhat = -1, idx_mask = -1;
  int wa_i[4], ba_i[4], wb_i[4], bb_i[4], g_i[4];
  int nwa = 0, nba = 0, nwb = 0, nbb = 0, ng = 0;
  for (int k = 0; k < n_in; ++k) {
    const int s = in_sizes[k];
    if      (s == 4194304) idx_rbf  = k;
    else if (s == 786432)  idx_rhat = k;
    else if (s == 262144)  idx_mask = k;
    else if (s == 24576)   idx_f1   = k;
    else if (s == 8192)    { if (idx_f0 < 0) idx_f0 = k; else if (nwb < 4) wb_i[nwb++] = k; }
    else if (s == 512)     { if (nwa < 4) wa_i[nwa++] = k; }
    else if (s == 32)      { if (nba < 4) ba_i[nba++] = k; }
    else if (s == 256)     { if (nbb < 4) bb_i[nbb++] = k; }
    else if (s == 16)      { if (ng  < 4) g_i[ng++]  = k; }
  }
  const bool ok = idx_f0 >= 0 && idx_f1 >= 0 && idx_rbf >= 0 && idx_rhat >= 0 &&
                  idx_mask >= 0 && nwa == 4 && nba == 4 && nwb == 4 && nbb == 4 && ng == 4;
  if (!ok) {
    idx_f0 = 1; idx_f1 = 2; idx_rbf = 3; idx_rhat = 4; idx_mask = 5;
    for (int q = 0; q < 4; ++q) {
      wa_i[q] = 6 + q*4; ba_i[q] = 7 + q*4; wb_i[q] = 8 + q*4; bb_i[q] = 9 + q*4;
      g_i[q] = 22 + q;
    }
  }
  float* ws = (float*)d_ws;                                 // 512*64 partial sums
  int* cnt = (int*)((char*)d_ws + 512*64*sizeof(float));    // 512 arrival counters
  hipMemsetAsync(d_ws, 0, 512*64*sizeof(float) + 512*sizeof(int), stream);
  tfn_fused<<<1024, 512, 0, stream>>>(
      (const float*)d_in[idx_f0],  (const float*)d_in[idx_f1],
      (const float*)d_in[idx_rbf], (const float*)d_in[idx_rhat],
      (const int*)d_in[idx_mask],
      (const float*)d_in[wa_i[0]], (const float*)d_in[ba_i[0]],
      (const float*)d_in[wb_i[0]], (const float*)d_in[bb_i[0]],
      (const float*)d_in[wa_i[1]], (const float*)d_in[ba_i[1]],
      (const float*)d_in[wb_i[1]], (const float*)d_in[bb_i[1]],
      (const float*)d_in[wa_i[2]], (const float*)d_in[ba_i[2]],
      (const float*)d_in[wb_i[2]], (const float*)d_in[bb_i[2]],
      (const float*)d_in[wa_i[3]], (const float*)d_in[ba_i[3]],
      (const float*)d_in[wb_i[3]], (const float*)d_in[bb_i[3]],
      (const float*)d_in[g_i[0]], (const float*)d_in[g_i[1]],
      (const float*)d_in[g_i[2]], (const float*)d_in[g_i[3]],
      ws, cnt, (float*)d_out);
}

// Round 16
// 179.177 us; speedup vs baseline: 1.0686x; 1.0686x over previous
//
#include <hip/hip_runtime.h>
#include <hip/hip_bf16.h>

#define NTOK 512
#define TJ 32
#define NHALF 8            // j-tiles per half (waves 0-7: j<256, waves 8-15: j>=256)
#define EPSF 1e-5f

typedef __attribute__((ext_vector_type(4))) float f32x4;
typedef __attribute__((ext_vector_type(8))) short bf16x8;
typedef __attribute__((ext_vector_type(4))) short bf16x4;

struct HL { short hi; short lo; };

__device__ __forceinline__ short f2bf(float x) {
  __hip_bfloat16 h = __float2bfloat16(x);
  return *reinterpret_cast<short*>(&h);
}
__device__ __forceinline__ float bf2f(short s) {
  unsigned int u = ((unsigned int)(unsigned short)s) << 16;
  return __uint_as_float(u);
}
// RNE split x ~= hi + lo (~17 mantissa bits combined)
__device__ __forceinline__ HL splitbf(float x) {
  HL r;
  r.hi = f2bf(x);
  r.lo = f2bf(x - bf2f(r.hi));
  return r;
}

// Per-half DOUBLE-BUFFERED main-loop LDS (R12-verbatim, 64000 B/half).
struct __align__(16) SMemHalf {
  float f0s[2][32*17];     // [buf][j][f], stride 17
  float f1s[2][32*49];     // [buf][j][c*3+x], stride 49
  float rhs[2][96];        // [buf][j*3+x]
  float maskf[2][32];
  short rbfHL[2][32*40];   // [buf][j][k]: k<16 hi, k>=16 lo; 80B row stride
  short Hh[2][128*40];     // [buf][h][j] bf16 hi, stride 40
  short Hl[2][128*40];     // lo
};
union __align__(16) SMemU {
  SMemHalf h[2];           // 128000 B main
  struct {                 // epilogue region (disjoint lifetime; ~22 KB)
    float ACCs[128*33];
    float biasR[128];
    float part[1024];
    float m00s[16], m10s[16], p01s[48], p11s[48], rawbs[48], nrms[16];
  } e;
};

// R12 EXACT structure (best measured: 74.7 us dispatch / 178.9 bench):
// ONE kernel, 512 blocks (one per i), 1024 threads = 16 waves, in-block
// j-split, 1-barrier-per-tile double-buffered pipeline, intra-block merge.
// SINGLE change this round: LHS(t) hoisted BEFORE phase A(t) -- both depend
// only on post-barrier state; LHS's ~11 independent scalar LDS loads issue
// first so their ~120cy latencies overlap A's MFMA+silu chain.
// Locked-in constraints from the session: NEVER launch_bounds(x,8) (reg wall,
// R3+R11: 32-VGPR alloc + 260-660 MB scratch); no __threadfence rendezvous
// (R9: ~380 us L2-writeback serialization); occupancy cap = 4 waves/SIMD.
__global__ __launch_bounds__(1024, 4) void tfn_kernel(
    const float* __restrict__ f0,  const float* __restrict__ f1,
    const float* __restrict__ rbf, const float* __restrict__ rhat,
    const int*  __restrict__ mask,
    const float* __restrict__ w00a, const float* __restrict__ b00a,
    const float* __restrict__ w00b, const float* __restrict__ b00b,
    const float* __restrict__ w10a, const float* __restrict__ b10a,
    const float* __restrict__ w10b, const float* __restrict__ b10b,
    const float* __restrict__ w01a, const float* __restrict__ b01a,
    const float* __restrict__ w01b, const float* __restrict__ b01b,
    const float* __restrict__ w11a, const float* __restrict__ b11a,
    const float* __restrict__ w11b, const float* __restrict__ b11b,
    const float* __restrict__ g0, const float* __restrict__ be0,
    const float* __restrict__ g1, const float* __restrict__ be1,
    float* __restrict__ out)
{
  __shared__ SMemU sm;
  const int i = blockIdx.x;
  const int t = threadIdx.x;          // 0..1023
  const int half = t >> 9;            // j-half this thread works on
  const int th = t & 511;             // thread id within half
  const int w8 = th >> 6;             // wave id within half, 0..7
  const int lane = t & 63;
  const int col = lane & 15;
  const int quad = lane >> 4;
  const int jbase = half * (NHALF * TJ);
  SMemHalf* smh = &sm.h[half];

  // ---- per-wave WA B-frags: bw1 = [Whi | Whi], bw2 = [Wlo | 0] ----
  bf16x8 bw1, bw2;
  float bav;
  {
    const int h = w8*16 + col;
    const float* wa = (w8 < 2) ? (w00a + h*16) : (w8 < 4) ? (w10a + (h-32)*16)
                    : (w8 < 6) ? (w01a + (h-64)*16) : (w11a + (h-96)*16);
    bav = (w8 < 2) ? b00a[h] : (w8 < 4) ? b10a[h-32] : (w8 < 6) ? b01a[h-64] : b11a[h-96];
    #pragma unroll
    for (int e = 0; e < 8; ++e) {
      HL s = splitbf(wa[(quad & 1)*8 + e]);
      bw1[e] = s.hi;
      bw2[e] = (quad < 2) ? s.lo : (short)0;
    }
  }

  // ---- per-lane LHS constants (wave-uniform branch selectors) ----
  int fdiv = 0, xrem = 0, cidx = 0;
  if (w8 >= 2 && w8 < 5) { const int idx = (w8-2)*16 + col; fdiv = idx/3; xrem = idx - 3*fdiv; }
  if (w8 >= 5) cidx = (w8-5)*16 + col;
  const int hb = (w8 == 0) ? 0 : (w8 == 1) ? 2 : (w8 < 5) ? 4 : 6;

  // f1 staging index precompute (within-half)
  int f1q0, f1r0, f1q1, f1r1, f1q2, f1r2;
  { int a = th;        f1q0 = a/48; f1r0 = a - 48*f1q0; }
  { int a = th + 512;  f1q1 = a/48; f1r1 = a - 48*f1q1; }
  { int a = th + 1024; f1q2 = a/48; f1r2 = a - 48*f1q2; }
  const int jrow = th >> 4, jfeat = th & 15;

  // ---- prologue: load tile 0, stage into buf 0, prefetch tile 1 ----
  float pf_f0, pf_f1_0, pf_f1_1, pf_f1_2, pf_rh = 0.f, pf_rbf;
  int pf_mk = 0;
  {
    pf_f0   = f0[(jbase + jrow)*16 + jfeat];
    pf_f1_0 = f1[jbase*48 + th]; pf_f1_1 = f1[jbase*48 + th + 512]; pf_f1_2 = f1[jbase*48 + th + 1024];
    if (th < 96) pf_rh = rhat[((size_t)i*NTOK + jbase)*3 + th];
    if (th < 32) pf_mk = mask[(size_t)i*NTOK + jbase + th];
    pf_rbf  = rbf[((size_t)i*NTOK + jbase + jrow)*16 + jfeat];

    smh->f0s[0][jrow*17 + jfeat] = pf_f0;
    smh->f1s[0][f1q0*49 + f1r0] = pf_f1_0;
    smh->f1s[0][f1q1*49 + f1r1] = pf_f1_1;
    smh->f1s[0][f1q2*49 + f1r2] = pf_f1_2;
    if (th < 96) smh->rhs[0][th] = pf_rh;
    if (th < 32) smh->maskf[0][th] = pf_mk ? 1.f : 0.f;
    HL s = splitbf(pf_rbf);
    smh->rbfHL[0][jrow*40 + jfeat]      = s.hi;
    smh->rbfHL[0][jrow*40 + 16 + jfeat] = s.lo;

    const int j0 = jbase + TJ;
    pf_f0   = f0[(j0 + jrow)*16 + jfeat];
    pf_f1_0 = f1[j0*48 + th]; pf_f1_1 = f1[j0*48 + th + 512]; pf_f1_2 = f1[j0*48 + th + 1024];
    if (th < 96) pf_rh = rhat[((size_t)i*NTOK + j0)*3 + th];
    if (th < 32) pf_mk = mask[(size_t)i*NTOK + j0 + th];
    pf_rbf  = rbf[((size_t)i*NTOK + j0 + jrow)*16 + jfeat];
  }
  __syncthreads();   // staging buf0 visible (both halves aligned)

  f32x4 acc0 = {0.f,0.f,0.f,0.f}, acc1 = {0.f,0.f,0.f,0.f};
  float biasp = 0.f;
  const f32x4 zc = {0.f,0.f,0.f,0.f};
  bf16x8 afh, afl;   // phase-B A-frag, produced by LHS(t), consumed by B(t) next iter

  for (int tile = 0; tile < NHALF; ++tile) {
    const int cur = tile & 1, nxt = cur ^ 1;

    // ---- 1. stage tile+1 into buf nxt (its readers finished at barrier t-1) ----
    if (tile + 1 < NHALF) {
      smh->f0s[nxt][jrow*17 + jfeat] = pf_f0;
      smh->f1s[nxt][f1q0*49 + f1r0] = pf_f1_0;
      smh->f1s[nxt][f1q1*49 + f1r1] = pf_f1_1;
      smh->f1s[nxt][f1q2*49 + f1r2] = pf_f1_2;
      if (th < 96) smh->rhs[nxt][th] = pf_rh;
      if (th < 32) smh->maskf[nxt][th] = pf_mk ? 1.f : 0.f;
      HL s = splitbf(pf_rbf);
      smh->rbfHL[nxt][jrow*40 + jfeat]      = s.hi;
      smh->rbfHL[nxt][jrow*40 + 16 + jfeat] = s.lo;
    }

    // ---- 2. issue prefetch of tile+2 ----
    if (tile + 2 < NHALF) {
      const int j0 = jbase + (tile+2)*TJ;
      pf_f0   = f0[(j0 + jrow)*16 + jfeat];
      pf_f1_0 = f1[j0*48 + th]; pf_f1_1 = f1[j0*48 + th + 512]; pf_f1_2 = f1[j0*48 + th + 1024];
      if (th < 96) pf_rh = rhat[((size_t)i*NTOK + j0)*3 + th];
      if (th < 32) pf_mk = mask[(size_t)i*NTOK + j0 + th];
      pf_rbf  = rbf[((size_t)i*NTOK + j0 + jrow)*16 + jfeat];
    }

    // ---- 3. phase B for tile-1: ACC += L^T * H (H[(tile-1)&1] = H[nxt]) ----
    if (tile > 0) {
      const bf16x8 b0h = *(const bf16x8*)&smh->Hh[nxt][(hb*16+col)*40 + quad*8];
      const bf16x8 b0l = *(const bf16x8*)&smh->Hl[nxt][(hb*16+col)*40 + quad*8];
      const bf16x8 b1h = *(const bf16x8*)&smh->Hh[nxt][((hb+1)*16+col)*40 + quad*8];
      const bf16x8 b1l = *(const bf16x8*)&smh->Hl[nxt][((hb+1)*16+col)*40 + quad*8];
      acc0 = __builtin_amdgcn_mfma_f32_16x16x32_bf16(afl, b0h, acc0, 0, 0, 0);
      acc0 = __builtin_amdgcn_mfma_f32_16x16x32_bf16(afh, b0l, acc0, 0, 0, 0);
      acc0 = __builtin_amdgcn_mfma_f32_16x16x32_bf16(afh, b0h, acc0, 0, 0, 0);
      acc1 = __builtin_amdgcn_mfma_f32_16x16x32_bf16(afl, b1h, acc1, 0, 0, 0);
      acc1 = __builtin_amdgcn_mfma_f32_16x16x32_bf16(afh, b1l, acc1, 0, 0, 0);
      acc1 = __builtin_amdgcn_mfma_f32_16x16x32_bf16(afh, b1h, acc1, 0, 0, 0);
    }

    // ---- 4. LHS(t) FIRST (hoisted): independent scalar LDS loads issue early ----
    {
      const int jb = quad*8;
      float mkv[8];
      { const float4 mk0 = *(const float4*)&smh->maskf[cur][jb];
        const float4 mk1 = *(const float4*)&smh->maskf[cur][jb + 4];
        mkv[0]=mk0.x; mkv[1]=mk0.y; mkv[2]=mk0.z; mkv[3]=mk0.w;
        mkv[4]=mk1.x; mkv[5]=mk1.y; mkv[6]=mk1.z; mkv[7]=mk1.w; }
      float v[8];
      if (w8 == 0) {
        #pragma unroll
        for (int jj = 0; jj < 8; ++jj) v[jj] = mkv[jj] * smh->f0s[cur][(jb+jj)*17 + col];
      } else if (w8 < 5) {
        float rwin[24];
        #pragma unroll
        for (int q4 = 0; q4 < 6; ++q4) {
          const float4 rr = *(const float4*)&smh->rhs[cur][jb*3 + q4*4];
          rwin[q4*4+0]=rr.x; rwin[q4*4+1]=rr.y; rwin[q4*4+2]=rr.z; rwin[q4*4+3]=rr.w;
        }
        if (w8 == 1) {
          #pragma unroll
          for (int jj = 0; jj < 8; ++jj) {
            const float* fr = &smh->f1s[cur][(jb+jj)*49 + col*3];
            v[jj] = mkv[jj] * (rwin[jj*3+0]*fr[0] + rwin[jj*3+1]*fr[1] + rwin[jj*3+2]*fr[2]);
          }
        } else {
          #pragma unroll
          for (int jj = 0; jj < 8; ++jj)
            v[jj] = mkv[jj] * smh->f0s[cur][(jb+jj)*17 + fdiv] * rwin[jj*3 + xrem];
        }
      } else {
        #pragma unroll
        for (int jj = 0; jj < 8; ++jj) v[jj] = mkv[jj] * smh->f1s[cur][(jb+jj)*49 + cidx];
      }
      #pragma unroll
      for (int jj = 0; jj < 8; ++jj) {
        biasp += v[jj];
        HL s = splitbf(v[jj]);
        afh[jj] = s.hi; afl[jj] = s.lo;
      }
    }

    // ---- 5. phase A: H[cur] = silu(rbf @ WA^T + ba) ----
    {
      const bf16x8 a0 = *(const bf16x8*)&smh->rbfHL[cur][col*40 + quad*8];
      const bf16x8 a1 = *(const bf16x8*)&smh->rbfHL[cur][(16+col)*40 + quad*8];
      f32x4 d0 = __builtin_amdgcn_mfma_f32_16x16x32_bf16(a0, bw1, zc, 0, 0, 0);
      d0 = __builtin_amdgcn_mfma_f32_16x16x32_bf16(a0, bw2, d0, 0, 0, 0);
      f32x4 d1 = __builtin_amdgcn_mfma_f32_16x16x32_bf16(a1, bw1, zc, 0, 0, 0);
      d1 = __builtin_amdgcn_mfma_f32_16x16x32_bf16(a1, bw2, d1, 0, 0, 0);
      bf16x4 hv, lv;
      #pragma unroll
      for (int r = 0; r < 4; ++r) {
        float p = d0[r] + bav;
        float s = p * __builtin_amdgcn_rcpf(1.f + __expf(-p));
        HL e2 = splitbf(s); hv[r] = e2.hi; lv[r] = e2.lo;
      }
      *(bf16x4*)&smh->Hh[cur][(w8*16+col)*40 + quad*4] = hv;
      *(bf16x4*)&smh->Hl[cur][(w8*16+col)*40 + quad*4] = lv;
      #pragma unroll
      for (int r = 0; r < 4; ++r) {
        float p = d1[r] + bav;
        float s = p * __builtin_amdgcn_rcpf(1.f + __expf(-p));
        HL e2 = splitbf(s); hv[r] = e2.hi; lv[r] = e2.lo;
      }
      *(bf16x4*)&smh->Hh[cur][(w8*16+col)*40 + 16 + quad*4] = hv;
      *(bf16x4*)&smh->Hl[cur][(w8*16+col)*40 + 16 + quad*4] = lv;
    }

    __syncthreads();   // H[cur] + staging[nxt] visible; all reads of [cur]/[nxt] done
  }

  // ---- final phase B for tile NHALF-1 (H[(NHALF-1)&1] = [1]) ----
  {
    const int lb = (NHALF-1) & 1;
    const bf16x8 b0h = *(const bf16x8*)&smh->Hh[lb][(hb*16+col)*40 + quad*8];
    const bf16x8 b0l = *(const bf16x8*)&smh->Hl[lb][(hb*16+col)*40 + quad*8];
    const bf16x8 b1h = *(const bf16x8*)&smh->Hh[lb][((hb+1)*16+col)*40 + quad*8];
    const bf16x8 b1l = *(const bf16x8*)&smh->Hl[lb][((hb+1)*16+col)*40 + quad*8];
    acc0 = __builtin_amdgcn_mfma_f32_16x16x32_bf16(afl, b0h, acc0, 0, 0, 0);
    acc0 = __builtin_amdgcn_mfma_f32_16x16x32_bf16(afh, b0l, acc0, 0, 0, 0);
    acc0 = __builtin_amdgcn_mfma_f32_16x16x32_bf16(afh, b0h, acc0, 0, 0, 0);
    acc1 = __builtin_amdgcn_mfma_f32_16x16x32_bf16(afl, b1h, acc1, 0, 0, 0);
    acc1 = __builtin_amdgcn_mfma_f32_16x16x32_bf16(afh, b1l, acc1, 0, 0, 0);
    acc1 = __builtin_amdgcn_mfma_f32_16x16x32_bf16(afh, b1h, acc1, 0, 0, 0);
  }

  __syncthreads();   // all main-loop LDS reads done -> union region reusable

  // ---- merge halves: half 0 writes, half 1 accumulates ----
  biasp += __shfl_xor(biasp, 16);
  biasp += __shfl_xor(biasp, 32);
  if (half == 0) {
    #pragma unroll
    for (int r = 0; r < 4; ++r) {
      sm.e.ACCs[(w8*16 + quad*4 + r)*33 + col]      = acc0[r];
      sm.e.ACCs[(w8*16 + quad*4 + r)*33 + 16 + col] = acc1[r];
    }
    if (lane < 16) sm.e.biasR[w8*16 + col] = biasp;
  }
  __syncthreads();
  if (half == 1) {
    #pragma unroll
    for (int r = 0; r < 4; ++r) {
      sm.e.ACCs[(w8*16 + quad*4 + r)*33 + col]      += acc0[r];
      sm.e.ACCs[(w8*16 + quad*4 + r)*33 + 16 + col] += acc1[r];
    }
    if (lane < 16) sm.e.biasR[w8*16 + col] += biasp;
  }
  __syncthreads();

  // ---- epilogue: second-layer contraction, 8-way split of the 16-long d loop ----
  {
    const int tt = t & 127, oct = t >> 7;   // oct 0..7
    float s = 0.f;
    if (tt < 16) {
      const int o = tt;
      #pragma unroll
      for (int dd = 0; dd < 2; ++dd) {
        const int d = oct + dd*8;
        const float* wrow = w00b + (d*16 + o)*32;
        float ss = 0.f;
        #pragma unroll
        for (int hh = 0; hh < 32; ++hh) ss += wrow[hh] * sm.e.ACCs[d*33 + hh];
        s += ss + b00b[d*16 + o] * sm.e.biasR[d];
      }
    } else if (tt < 32) {
      const int o = tt - 16;
      #pragma unroll
      for (int dd = 0; dd < 2; ++dd) {
        const int c = oct + dd*8, m = 16 + c;
        const float* wrow = w10b + (c*16 + o)*32;
        float ss = 0.f;
        #pragma unroll
        for (int hh = 0; hh < 32; ++hh) ss += wrow[hh] * sm.e.ACCs[m*33 + hh];
        s += ss + b10b[c*16 + o] * sm.e.biasR[m];
      }
    } else if (tt < 80) {
      const int idx = tt - 32, g = idx/3, x = idx - 3*g;
      #pragma unroll
      for (int dd = 0; dd < 2; ++dd) {
        const int f = oct + dd*8, m = 32 + f*3 + x;
        const float* wrow = w01b + (f*16 + g)*32;
        float ss = 0.f;
        #pragma unroll
        for (int hh = 0; hh < 32; ++hh) ss += wrow[hh] * sm.e.ACCs[m*33 + hh];
        s += ss + b01b[f*16 + g] * sm.e.biasR[m];
      }
    } else {
      const int idx = tt - 80, g = idx/3, x = idx - 3*g;
      #pragma unroll
      for (int dd = 0; dd < 2; ++dd) {
        const int k = oct + dd*8, m = 80 + k*3 + x;
        const float* wrow = w11b + (k*16 + g)*32;
        float ss = 0.f;
        #pragma unroll
        for (int hh = 0; hh < 32; ++hh) ss += wrow[hh] * sm.e.ACCs[m*33 + hh];
        s += ss + b11b[k*16 + g] * sm.e.biasR[m];
      }
    }
    sm.e.part[t] = s;
  }
  __syncthreads();

  if (t < 128) {
    float s = 0.f;
    #pragma unroll
    for (int k = 0; k < 8; ++k) s += sm.e.part[t + 128*k];
    if (t < 16) sm.e.m00s[t] = s;
    else if (t < 32) sm.e.m10s[t-16] = s;
    else if (t < 80) sm.e.p01s[t-32] = s;
    else sm.e.p11s[t-80] = s;
  }
  __syncthreads();

  if (t < 16) {
    float vv = sm.e.m00s[t] + sm.e.m10s[t];
    float mu = 0.f;
    #pragma unroll
    for (int k = 0; k < 16; ++k) mu += sm.e.m00s[k] + sm.e.m10s[k];
    mu *= (1.f/16.f);
    float var = 0.f;
    #pragma unroll
    for (int k = 0; k < 16; ++k) { float d = sm.e.m00s[k] + sm.e.m10s[k] - mu; var += d*d; }
    var *= (1.f/16.f);
    out[(size_t)i*16 + t] = (vv - mu) * rsqrtf(var + EPSF) * g0[t] + be0[t];
    float r0v = sm.e.p01s[t*3+0] + sm.e.p11s[t*3+0];
    float r1v = sm.e.p01s[t*3+1] + sm.e.p11s[t*3+1];
    float r2v = sm.e.p01s[t*3+2] + sm.e.p11s[t*3+2];
    sm.e.rawbs[t*3+0] = r0v; sm.e.rawbs[t*3+1] = r1v; sm.e.rawbs[t*3+2] = r2v;
    sm.e.nrms[t] = fmaxf(sqrtf(r0v*r0v + r1v*r1v + r2v*r2v), 1e-8f);
  }
  __syncthreads();
  if (t < 16) {
    float mu = 0.f;
    #pragma unroll
    for (int k = 0; k < 16; ++k) mu += sm.e.nrms[k];
    mu *= (1.f/16.f);
    float var = 0.f;
    #pragma unroll
    for (int k = 0; k < 16; ++k) { float d = sm.e.nrms[k] - mu; var += d*d; }
    var *= (1.f/16.f);
    const float ln = (sm.e.nrms[t] - mu) * rsqrtf(var + EPSF) * g1[t] + be1[t];
    const float scale = ln / sm.e.nrms[t];
    const size_t base = (size_t)NTOK*16 + (size_t)i*48 + t*3;
    out[base+0] = sm.e.rawbs[t*3+0] * scale;
    out[base+1] = sm.e.rawbs[t*3+1] * scale;
    out[base+2] = sm.e.rawbs[t*3+2] * scale;
  }
}

extern "C" void kernel_launch(void* const* d_in, const int* in_sizes, int n_in,
                              void* d_out, int out_size, void* d_ws, size_t ws_size,
                              hipStream_t stream) {
  int idx_f0 = -1, idx_f1 = -1, idx_rbf = -1, idx_rhat = -1, idx_mask = -1;
  int wa_i[4], ba_i[4], wb_i[4], bb_i[4], g_i[4];
  int nwa = 0, nba = 0, nwb = 0, nbb = 0, ng = 0;
  for (int k = 0; k < n_in; ++k) {
    const int s = in_sizes[k];
    if      (s == 4194304) idx_rbf  = k;
    else if (s == 786432)  idx_rhat = k;
    else if (s == 262144)  idx_mask = k;
    else if (s == 24576)   idx_f1   = k;
    else if (s == 8192)    { if (idx_f0 < 0) idx_f0 = k; else if (nwb < 4) wb_i[nwb++] = k; }
    else if (s == 512)     { if (nwa < 4) wa_i[nwa++] = k; }
    else if (s == 32)      { if (nba < 4) ba_i[nba++] = k; }
    else if (s == 256)     { if (nbb < 4) bb_i[nbb++] = k; }
    else if (s == 16)      { if (ng  < 4) g_i[ng++]  = k; }
  }
  const bool ok = idx_f0 >= 0 && idx_f1 >= 0 && idx_rbf >= 0 && idx_rhat >= 0 &&
                  idx_mask >= 0 && nwa == 4 && nba == 4 && nwb == 4 && nbb == 4 && ng == 4;
  if (!ok) {
    idx_f0 = 1; idx_f1 = 2; idx_rbf = 3; idx_rhat = 4; idx_mask = 5;
    for (int q = 0; q < 4; ++q) {
      wa_i[q] = 6 + q*4; ba_i[q] = 7 + q*4; wb_i[q] = 8 + q*4; bb_i[q] = 9 + q*4;
      g_i[q] = 22 + q;
    }
  }
  tfn_kernel<<<512, 1024, 0, stream>>>(
      (const float*)d_in[idx_f0],  (const float*)d_in[idx_f1],
      (const float*)d_in[idx_rbf], (const float*)d_in[idx_rhat],
      (const int*)d_in[idx_mask],
      (const float*)d_in[wa_i[0]], (const float*)d_in[ba_i[0]],
      (const float*)d_in[wb_i[0]], (const float*)d_in[bb_i[0]],
      (const float*)d_in[wa_i[1]], (const float*)d_in[ba_i[1]],
      (const float*)d_in[wb_i[1]], (const float*)d_in[bb_i[1]],
      (const float*)d_in[wa_i[2]], (const float*)d_in[ba_i[2]],
      (const float*)d_in[wb_i[2]], (const float*)d_in[bb_i[2]],
      (const float*)d_in[wa_i[3]], (const float*)d_in[ba_i[3]],
      (const float*)d_in[wb_i[3]], (const float*)d_in[bb_i[3]],
      (const float*)d_in[g_i[0]], (const float*)d_in[g_i[1]],
      (const float*)d_in[g_i[2]], (const float*)d_in[g_i[3]],
      (float*)d_out);
}

// Round 17
// 169.841 us; speedup vs baseline: 1.1273x; 1.0550x over previous
//
#include <hip/hip_runtime.h>
#include <hip/hip_bf16.h>

#define NTOK 512
#define TJ 32
#define NHALF 8            // j-tiles per half (waves 0-7: j<256, waves 8-15: j>=256)
#define EPSF 1e-5f

typedef __attribute__((ext_vector_type(4))) float f32x4;
typedef __attribute__((ext_vector_type(8))) short bf16x8;
typedef __attribute__((ext_vector_type(4))) short bf16x4;

struct HL { short hi; short lo; };

__device__ __forceinline__ short f2bf(float x) {
  __hip_bfloat16 h = __float2bfloat16(x);
  return *reinterpret_cast<short*>(&h);
}
__device__ __forceinline__ float bf2f(short s) {
  unsigned int u = ((unsigned int)(unsigned short)s) << 16;
  return __uint_as_float(u);
}
// RNE split x ~= hi + lo (~17 mantissa bits combined)
__device__ __forceinline__ HL splitbf(float x) {
  HL r;
  r.hi = f2bf(x);
  r.lo = f2bf(x - bf2f(r.hi));
  return r;
}

// Per-half SINGLE-BUFFERED main-loop LDS (32000 B each; 64000 B/block so TWO
// 1024-thread blocks fit in 160 KB/CU -- the LDS half of the occupancy unlock).
struct __align__(16) SMemHalf {
  float f0s[32*17];      // [j][f], stride 17
  float f1s[32*49];      // [j][c*3+x], stride 49
  float rhs[96];         // [j*3+x]
  float maskf[32];
  short rbfHL[32*40];    // [j][k]: k<16 hi, k>=16 lo; 80B row stride
  short Hh[128*40];      // [h][j] bf16 hi, stride 40
  short Hl[128*40];      // lo
};
union __align__(16) SMemU {
  SMemHalf h[2];         // 64000 B main
  struct {               // epilogue region (disjoint lifetime; ~22 KB)
    float ACCs[128*33];
    float biasR[128];
    float part[1024];
    float m00s[16], m10s[16], p01s[48], p11s[48], rawbs[48], nrms[16];
  } e;
};

// R10's measured structure (75.2 us; 512 blocks x 1024 thr, in-block j-split,
// 2 barriers/tile, intra-block merge) with ONE change: the LHS is STREAMED --
// rwin[24]/mkv[8]/v[8] scratch arrays replaced by per-element scalar LDS reads
// with fused bias-add + split. Identical values, identical op order. Purpose:
// cut peak arch VGPRs to <=56 so total (arch+8 acc) <= 64 = the 8-waves/SIMD
// boundary -> 2 blocks/CU -> 32 waves/CU. R13 proved this family can compile
// at 56 arch; R13's LDS (127.5 KB) was what masked the occupancy gain.
// Budget stays 128 regs (launch_bounds(1024,4)) -- spill impossible; if the
// allocator lands 57-64 arch the kernel degenerates to exactly R10 (neutral).
// Locked-in: NEVER launch_bounds(x,8) (R3/R11: forced 32-reg + 260-660 MB
// scratch); no __threadfence rendezvous (R9: ~380 us).
__global__ __launch_bounds__(1024, 4) void tfn_kernel(
    const float* __restrict__ f0,  const float* __restrict__ f1,
    const float* __restrict__ rbf, const float* __restrict__ rhat,
    const int*  __restrict__ mask,
    const float* __restrict__ w00a, const float* __restrict__ b00a,
    const float* __restrict__ w00b, const float* __restrict__ b00b,
    const float* __restrict__ w10a, const float* __restrict__ b10a,
    const float* __restrict__ w10b, const float* __restrict__ b10b,
    const float* __restrict__ w01a, const float* __restrict__ b01a,
    const float* __restrict__ w01b, const float* __restrict__ b01b,
    const float* __restrict__ w11a, const float* __restrict__ b11a,
    const float* __restrict__ w11b, const float* __restrict__ b11b,
    const float* __restrict__ g0, const float* __restrict__ be0,
    const float* __restrict__ g1, const float* __restrict__ be1,
    float* __restrict__ out)
{
  __shared__ SMemU sm;
  const int i = blockIdx.x;
  const int t = threadIdx.x;          // 0..1023
  const int half = t >> 9;            // j-half this thread works on
  const int th = t & 511;             // thread id within half
  const int w8 = th >> 6;             // wave id within half, 0..7
  const int lane = t & 63;
  const int col = lane & 15;
  const int quad = lane >> 4;
  const int jbase = half * (NHALF * TJ);
  SMemHalf* smh = &sm.h[half];

  // ---- per-wave WA B-frags: bw1 = [Whi | Whi], bw2 = [Wlo | 0] ----
  bf16x8 bw1, bw2;
  float bav;
  {
    const int h = w8*16 + col;
    const float* wa = (w8 < 2) ? (w00a + h*16) : (w8 < 4) ? (w10a + (h-32)*16)
                    : (w8 < 6) ? (w01a + (h-64)*16) : (w11a + (h-96)*16);
    bav = (w8 < 2) ? b00a[h] : (w8 < 4) ? b10a[h-32] : (w8 < 6) ? b01a[h-64] : b11a[h-96];
    #pragma unroll
    for (int e = 0; e < 8; ++e) {
      HL s = splitbf(wa[(quad & 1)*8 + e]);
      bw1[e] = s.hi;
      bw2[e] = (quad < 2) ? s.lo : (short)0;
    }
  }

  // ---- per-lane LHS constants (wave-uniform branch selectors) ----
  int fdiv = 0, xrem = 0, cidx = 0;
  if (w8 >= 2 && w8 < 5) { const int idx = (w8-2)*16 + col; fdiv = idx/3; xrem = idx - 3*fdiv; }
  if (w8 >= 5) cidx = (w8-5)*16 + col;
  const int hb = (w8 == 0) ? 0 : (w8 == 1) ? 2 : (w8 < 5) ? 4 : 6;

  // f1 staging index precompute (within-half)
  int f1q0, f1r0, f1q1, f1r1, f1q2, f1r2;
  { int a = th;        f1q0 = a/48; f1r0 = a - 48*f1q0; }
  { int a = th + 512;  f1q1 = a/48; f1r1 = a - 48*f1q1; }
  { int a = th + 1024; f1q2 = a/48; f1r2 = a - 48*f1q2; }
  const int jrow = th >> 4, jfeat = th & 15;

  // ---- prefetch tile 0 of this half ----
  float pf_f0, pf_f1_0, pf_f1_1, pf_f1_2, pf_rh = 0.f, pf_rbf;
  int pf_mk = 0;
  {
    pf_f0   = f0[(jbase + jrow)*16 + jfeat];
    pf_f1_0 = f1[jbase*48 + th]; pf_f1_1 = f1[jbase*48 + th + 512]; pf_f1_2 = f1[jbase*48 + th + 1024];
    if (th < 96) pf_rh = rhat[((size_t)i*NTOK + jbase)*3 + th];
    if (th < 32) pf_mk = mask[(size_t)i*NTOK + jbase + th];
    pf_rbf  = rbf[((size_t)i*NTOK + jbase + jrow)*16 + jfeat];
  }

  f32x4 acc0 = {0.f,0.f,0.f,0.f}, acc1 = {0.f,0.f,0.f,0.f};
  float biasp = 0.f;
  const f32x4 zc = {0.f,0.f,0.f,0.f};

  for (int tile = 0; tile < NHALF; ++tile) {
    // ---- stage regs -> this half's LDS ----
    smh->f0s[jrow*17 + jfeat] = pf_f0;
    smh->f1s[f1q0*49 + f1r0] = pf_f1_0;
    smh->f1s[f1q1*49 + f1r1] = pf_f1_1;
    smh->f1s[f1q2*49 + f1r2] = pf_f1_2;
    if (th < 96) smh->rhs[th] = pf_rh;
    if (th < 32) smh->maskf[th] = pf_mk ? 1.f : 0.f;
    { HL s = splitbf(pf_rbf);
      smh->rbfHL[jrow*40 + jfeat]      = s.hi;
      smh->rbfHL[jrow*40 + 16 + jfeat] = s.lo; }
    __syncthreads();   // staging visible (both halves in lockstep)

    // ---- prefetch tile+1 ----
    if (tile + 1 < NHALF) {
      const int j0 = jbase + (tile+1)*TJ;
      pf_f0   = f0[(j0 + jrow)*16 + jfeat];
      pf_f1_0 = f1[j0*48 + th]; pf_f1_1 = f1[j0*48 + th + 512]; pf_f1_2 = f1[j0*48 + th + 1024];
      if (th < 96) pf_rh = rhat[((size_t)i*NTOK + j0)*3 + th];
      if (th < 32) pf_mk = mask[(size_t)i*NTOK + j0 + th];
      pf_rbf  = rbf[((size_t)i*NTOK + j0 + jrow)*16 + jfeat];
    }

    // ---- phase A: H = silu(rbf @ WA^T + ba) ----
    {
      const bf16x8 a0 = *(const bf16x8*)&smh->rbfHL[col*40 + quad*8];
      const bf16x8 a1 = *(const bf16x8*)&smh->rbfHL[(16+col)*40 + quad*8];
      f32x4 d0 = __builtin_amdgcn_mfma_f32_16x16x32_bf16(a0, bw1, zc, 0, 0, 0);
      d0 = __builtin_amdgcn_mfma_f32_16x16x32_bf16(a0, bw2, d0, 0, 0, 0);
      f32x4 d1 = __builtin_amdgcn_mfma_f32_16x16x32_bf16(a1, bw1, zc, 0, 0, 0);
      d1 = __builtin_amdgcn_mfma_f32_16x16x32_bf16(a1, bw2, d1, 0, 0, 0);
      bf16x4 hv, lv;
      #pragma unroll
      for (int r = 0; r < 4; ++r) {
        float p = d0[r] + bav;
        float s = p * __builtin_amdgcn_rcpf(1.f + __expf(-p));
        HL e2 = splitbf(s); hv[r] = e2.hi; lv[r] = e2.lo;
      }
      *(bf16x4*)&smh->Hh[(w8*16+col)*40 + quad*4] = hv;
      *(bf16x4*)&smh->Hl[(w8*16+col)*40 + quad*4] = lv;
      #pragma unroll
      for (int r = 0; r < 4; ++r) {
        float p = d1[r] + bav;
        float s = p * __builtin_amdgcn_rcpf(1.f + __expf(-p));
        HL e2 = splitbf(s); hv[r] = e2.hi; lv[r] = e2.lo;
      }
      *(bf16x4*)&smh->Hh[(w8*16+col)*40 + 16 + quad*4] = hv;
      *(bf16x4*)&smh->Hl[(w8*16+col)*40 + 16 + quad*4] = lv;
    }

    // ---- LHS: STREAMED per-lane phase-B A-frag (no rwin/mkv/v arrays;
    //      per-element scalar LDS reads, fused bias-add + split; identical
    //      values and op order to R10's array version) ----
    bf16x8 afh, afl;
    {
      const int jb = quad*8;
      #pragma unroll
      for (int jj = 0; jj < 8; ++jj) {
        const int j = jb + jj;
        const float mk = smh->maskf[j];
        float v;
        if (w8 == 0) {
          v = mk * smh->f0s[j*17 + col];
        } else if (w8 == 1) {
          const float* rp = &smh->rhs[j*3];
          const float* fr = &smh->f1s[j*49 + col*3];
          v = mk * (rp[0]*fr[0] + rp[1]*fr[1] + rp[2]*fr[2]);
        } else if (w8 < 5) {
          v = mk * smh->f0s[j*17 + fdiv] * smh->rhs[j*3 + xrem];
        } else {
          v = mk * smh->f1s[j*49 + cidx];
        }
        biasp += v;
        HL s = splitbf(v);
        afh[jj] = s.hi; afl[jj] = s.lo;
      }
    }
    __syncthreads();   // H visible; staging fully consumed

    // ---- phase B: ACC += L^T * H ----
    {
      const bf16x8 b0h = *(const bf16x8*)&smh->Hh[(hb*16+col)*40 + quad*8];
      const bf16x8 b0l = *(const bf16x8*)&smh->Hl[(hb*16+col)*40 + quad*8];
      const bf16x8 b1h = *(const bf16x8*)&smh->Hh[((hb+1)*16+col)*40 + quad*8];
      const bf16x8 b1l = *(const bf16x8*)&smh->Hl[((hb+1)*16+col)*40 + quad*8];
      acc0 = __builtin_amdgcn_mfma_f32_16x16x32_bf16(afl, b0h, acc0, 0, 0, 0);
      acc0 = __builtin_amdgcn_mfma_f32_16x16x32_bf16(afh, b0l, acc0, 0, 0, 0);
      acc0 = __builtin_amdgcn_mfma_f32_16x16x32_bf16(afh, b0h, acc0, 0, 0, 0);
      acc1 = __builtin_amdgcn_mfma_f32_16x16x32_bf16(afl, b1h, acc1, 0, 0, 0);
      acc1 = __builtin_amdgcn_mfma_f32_16x16x32_bf16(afh, b1l, acc1, 0, 0, 0);
      acc1 = __builtin_amdgcn_mfma_f32_16x16x32_bf16(afh, b1h, acc1, 0, 0, 0);
    }
  }

  __syncthreads();   // all main-loop LDS reads done -> union region reusable

  // ---- merge halves: half 0 writes, half 1 accumulates ----
  biasp += __shfl_xor(biasp, 16);
  biasp += __shfl_xor(biasp, 32);
  if (half == 0) {
    #pragma unroll
    for (int r = 0; r < 4; ++r) {
      sm.e.ACCs[(w8*16 + quad*4 + r)*33 + col]      = acc0[r];
      sm.e.ACCs[(w8*16 + quad*4 + r)*33 + 16 + col] = acc1[r];
    }
    if (lane < 16) sm.e.biasR[w8*16 + col] = biasp;
  }
  __syncthreads();
  if (half == 1) {
    #pragma unroll
    for (int r = 0; r < 4; ++r) {
      sm.e.ACCs[(w8*16 + quad*4 + r)*33 + col]      += acc0[r];
      sm.e.ACCs[(w8*16 + quad*4 + r)*33 + 16 + col] += acc1[r];
    }
    if (lane < 16) sm.e.biasR[w8*16 + col] += biasp;
  }
  __syncthreads();

  // ---- epilogue: second-layer contraction, 8-way split of the 16-long d loop ----
  {
    const int tt = t & 127, oct = t >> 7;   // oct 0..7
    float s = 0.f;
    if (tt < 16) {
      const int o = tt;
      #pragma unroll
      for (int dd = 0; dd < 2; ++dd) {
        const int d = oct + dd*8;
        const float* wrow = w00b + (d*16 + o)*32;
        float ss = 0.f;
        #pragma unroll
        for (int hh = 0; hh < 32; ++hh) ss += wrow[hh] * sm.e.ACCs[d*33 + hh];
        s += ss + b00b[d*16 + o] * sm.e.biasR[d];
      }
    } else if (tt < 32) {
      const int o = tt - 16;
      #pragma unroll
      for (int dd = 0; dd < 2; ++dd) {
        const int c = oct + dd*8, m = 16 + c;
        const float* wrow = w10b + (c*16 + o)*32;
        float ss = 0.f;
        #pragma unroll
        for (int hh = 0; hh < 32; ++hh) ss += wrow[hh] * sm.e.ACCs[m*33 + hh];
        s += ss + b10b[c*16 + o] * sm.e.biasR[m];
      }
    } else if (tt < 80) {
      const int idx = tt - 32, g = idx/3, x = idx - 3*g;
      #pragma unroll
      for (int dd = 0; dd < 2; ++dd) {
        const int f = oct + dd*8, m = 32 + f*3 + x;
        const float* wrow = w01b + (f*16 + g)*32;
        float ss = 0.f;
        #pragma unroll
        for (int hh = 0; hh < 32; ++hh) ss += wrow[hh] * sm.e.ACCs[m*33 + hh];
        s += ss + b01b[f*16 + g] * sm.e.biasR[m];
      }
    } else {
      const int idx = tt - 80, g = idx/3, x = idx - 3*g;
      #pragma unroll
      for (int dd = 0; dd < 2; ++dd) {
        const int k = oct + dd*8, m = 80 + k*3 + x;
        const float* wrow = w11b + (k*16 + g)*32;
        float ss = 0.f;
        #pragma unroll
        for (int hh = 0; hh < 32; ++hh) ss += wrow[hh] * sm.e.ACCs[m*33 + hh];
        s += ss + b11b[k*16 + g] * sm.e.biasR[m];
      }
    }
    sm.e.part[t] = s;
  }
  __syncthreads();

  if (t < 128) {
    float s = 0.f;
    #pragma unroll
    for (int k = 0; k < 8; ++k) s += sm.e.part[t + 128*k];
    if (t < 16) sm.e.m00s[t] = s;
    else if (t < 32) sm.e.m10s[t-16] = s;
    else if (t < 80) sm.e.p01s[t-32] = s;
    else sm.e.p11s[t-80] = s;
  }
  __syncthreads();

  if (t < 16) {
    float vv = sm.e.m00s[t] + sm.e.m10s[t];
    float mu = 0.f;
    #pragma unroll
    for (int k = 0; k < 16; ++k) mu += sm.e.m00s[k] + sm.e.m10s[k];
    mu *= (1.f/16.f);
    float var = 0.f;
    #pragma unroll
    for (int k = 0; k < 16; ++k) { float d = sm.e.m00s[k] + sm.e.m10s[k] - mu; var += d*d; }
    var *= (1.f/16.f);
    out[(size_t)i*16 + t] = (vv - mu) * rsqrtf(var + EPSF) * g0[t] + be0[t];
    float r0v = sm.e.p01s[t*3+0] + sm.e.p11s[t*3+0];
    float r1v = sm.e.p01s[t*3+1] + sm.e.p11s[t*3+1];
    float r2v = sm.e.p01s[t*3+2] + sm.e.p11s[t*3+2];
    sm.e.rawbs[t*3+0] = r0v; sm.e.rawbs[t*3+1] = r1v; sm.e.rawbs[t*3+2] = r2v;
    sm.e.nrms[t] = fmaxf(sqrtf(r0v*r0v + r1v*r1v + r2v*r2v), 1e-8f);
  }
  __syncthreads();
  if (t < 16) {
    float mu = 0.f;
    #pragma unroll
    for (int k = 0; k < 16; ++k) mu += sm.e.nrms[k];
    mu *= (1.f/16.f);
    float var = 0.f;
    #pragma unroll
    for (int k = 0; k < 16; ++k) { float d = sm.e.nrms[k] - mu; var += d*d; }
    var *= (1.f/16.f);
    const float ln = (sm.e.nrms[t] - mu) * rsqrtf(var + EPSF) * g1[t] + be1[t];
    const float scale = ln / sm.e.nrms[t];
    const size_t base = (size_t)NTOK*16 + (size_t)i*48 + t*3;
    out[base+0] = sm.e.rawbs[t*3+0] * scale;
    out[base+1] = sm.e.rawbs[t*3+1] * scale;
    out[base+2] = sm.e.rawbs[t*3+2] * scale;
  }
}

extern "C" void kernel_launch(void* const* d_in, const int* in_sizes, int n_in,
                              void* d_out, int out_size, void* d_ws, size_t ws_size,
                              hipStream_t stream) {
  int idx_f0 = -1, idx_f1 = -1, idx_rbf = -1, idx_rhat = -1, idx_mask = -1;
  int wa_i[4], ba_i[4], wb_i[4], bb_i[4], g_i[4];
  int nwa = 0, nba = 0, nwb = 0, nbb = 0, ng = 0;
  for (int k = 0; k < n_in; ++k) {
    const int s = in_sizes[k];
    if      (s == 4194304) idx_rbf  = k;
    else if (s == 786432)  idx_rhat = k;
    else if (s == 262144)  idx_mask = k;
    else if (s == 24576)   idx_f1   = k;
    else if (s == 8192)    { if (idx_f0 < 0) idx_f0 = k; else if (nwb < 4) wb_i[nwb++] = k; }
    else if (s == 512)     { if (nwa < 4) wa_i[nwa++] = k; }
    else if (s == 32)      { if (nba < 4) ba_i[nba++] = k; }
    else if (s == 256)     { if (nbb < 4) bb_i[nbb++] = k; }
    else if (s == 16)      { if (ng  < 4) g_i[ng++]  = k; }
  }
  const bool ok = idx_f0 >= 0 && idx_f1 >= 0 && idx_rbf >= 0 && idx_rhat >= 0 &&
                  idx_mask >= 0 && nwa == 4 && nba == 4 && nwb == 4 && nbb == 4 && ng == 4;
  if (!ok) {
    idx_f0 = 1; idx_f1 = 2; idx_rbf = 3; idx_rhat = 4; idx_mask = 5;
    for (int q = 0; q < 4; ++q) {
      wa_i[q] = 6 + q*4; ba_i[q] = 7 + q*4; wb_i[q] = 8 + q*4; bb_i[q] = 9 + q*4;
      g_i[q] = 22 + q;
    }
  }
  tfn_kernel<<<512, 1024, 0, stream>>>(
      (const float*)d_in[idx_f0],  (const float*)d_in[idx_f1],
      (const float*)d_in[idx_rbf], (const float*)d_in[idx_rhat],
      (const int*)d_in[idx_mask],
      (const float*)d_in[wa_i[0]], (const float*)d_in[ba_i[0]],
      (const float*)d_in[wb_i[0]], (const float*)d_in[bb_i[0]],
      (const float*)d_in[wa_i[1]], (const float*)d_in[ba_i[1]],
      (const float*)d_in[wb_i[1]], (const float*)d_in[bb_i[1]],
      (const float*)d_in[wa_i[2]], (const float*)d_in[ba_i[2]],
      (const float*)d_in[wb_i[2]], (const float*)d_in[bb_i[2]],
      (const float*)d_in[wa_i[3]], (const float*)d_in[ba_i[3]],
      (const float*)d_in[wb_i[3]], (const float*)d_in[bb_i[3]],
      (const float*)d_in[g_i[0]], (const float*)d_in[g_i[1]],
      (const float*)d_in[g_i[2]], (const float*)d_in[g_i[3]],
      (float*)d_out);
}

// Round 18
// 168.748 us; speedup vs baseline: 1.1346x; 1.0065x over previous
//
#include <hip/hip_runtime.h>
#include <hip/hip_bf16.h>

#define NTOK 512
#define TJ 32
#define NHALF 8            // j-tiles per half (waves 0-7: j<256, waves 8-15: j>=256)
#define EPSF 1e-5f

typedef __attribute__((ext_vector_type(4))) float f32x4;
typedef __attribute__((ext_vector_type(8))) short bf16x8;
typedef __attribute__((ext_vector_type(4))) short bf16x4;

struct HL { short hi; short lo; };

__device__ __forceinline__ short f2bf(float x) {
  __hip_bfloat16 h = __float2bfloat16(x);
  return *reinterpret_cast<short*>(&h);
}
__device__ __forceinline__ float bf2f(short s) {
  unsigned int u = ((unsigned int)(unsigned short)s) << 16;
  return __uint_as_float(u);
}
// RNE split x ~= hi + lo (~17 mantissa bits combined)
__device__ __forceinline__ HL splitbf(float x) {
  HL r;
  r.hi = f2bf(x);
  r.lo = f2bf(x - bf2f(r.hi));
  return r;
}

// Per-half SINGLE-BUFFERED main-loop LDS (31872 B each; 63744 B/block so TWO
// 1024-thread blocks fit in 160 KB/CU).
// f1s stride is 48 (UNPADDED): the LDS write address for the coalesced global
// load f1[j0*48 + th + {0,512,1024}] is simply f1s[th + {0,512,1024}] -- this
// deletes the six loop-invariant div-by-48 index registers (R17's last 4-reg
// gap to the 64-total occupancy boundary). Cost: w8==1 / w8>=5 scalar reads go
// 2-way -> 4-way bank conflict (quad*384 = 0 mod 32) -- ~50 reads/tile, noise.
struct __align__(16) SMemHalf {
  float f0s[32*17];      // [j][f], stride 17
  float f1s[32*48];      // [j][c*3+x], stride 48 (unpadded, linear-writable)
  float rhs[96];         // [j*3+x]
  float maskf[32];
  short rbfHL[32*40];    // [j][k]: k<16 hi, k>=16 lo; 80B row stride
  short Hh[128*40];      // [h][j] bf16 hi, stride 40
  short Hl[128*40];      // lo
};
union __align__(16) SMemU {
  SMemHalf h[2];         // 63744 B main
  struct {               // epilogue region (disjoint lifetime; ~22 KB)
    float ACCs[128*33];
    float biasR[128];
    float part[1024];
    float m00s[16], m10s[16], p01s[48], p11s[48], rawbs[48], nrms[16];
  } e;
};

// R17's measured structure (64.2 us steady / 169.8 bench best; 512 blocks x
// 1024 thr, in-block j-split, 2 barriers/tile, streamed LHS, intra-block
// merge) with ONE change: unpadded f1s (see above) to delete the 6 index
// registers. R17 compiled at 60 arch + 8 acc = 68 total (4 waves/SIMD);
// target <= 56 arch -> total <= 64 -> 8 waves/SIMD -> 2 blocks/CU (LDS fits).
// R13 proved 56-arch is achievable for this family under (1024,4).
// Locked-in: NEVER launch_bounds(x,8) (R3/R11 pathological 32-reg + scratch);
// no __threadfence rendezvous (R9: ~380 us L2-writeback serialization).
__global__ __launch_bounds__(1024, 4) void tfn_kernel(
    const float* __restrict__ f0,  const float* __restrict__ f1,
    const float* __restrict__ rbf, const float* __restrict__ rhat,
    const int*  __restrict__ mask,
    const float* __restrict__ w00a, const float* __restrict__ b00a,
    const float* __restrict__ w00b, const float* __restrict__ b00b,
    const float* __restrict__ w10a, const float* __restrict__ b10a,
    const float* __restrict__ w10b, const float* __restrict__ b10b,
    const float* __restrict__ w01a, const float* __restrict__ b01a,
    const float* __restrict__ w01b, const float* __restrict__ b01b,
    const float* __restrict__ w11a, const float* __restrict__ b11a,
    const float* __restrict__ w11b, const float* __restrict__ b11b,
    const float* __restrict__ g0, const float* __restrict__ be0,
    const float* __restrict__ g1, const float* __restrict__ be1,
    float* __restrict__ out)
{
  __shared__ SMemU sm;
  const int i = blockIdx.x;
  const int t = threadIdx.x;          // 0..1023
  const int half = t >> 9;            // j-half this thread works on
  const int th = t & 511;             // thread id within half
  const int w8 = th >> 6;             // wave id within half, 0..7
  const int lane = t & 63;
  const int col = lane & 15;
  const int quad = lane >> 4;
  const int jbase = half * (NHALF * TJ);
  SMemHalf* smh = &sm.h[half];

  // ---- per-wave WA B-frags: bw1 = [Whi | Whi], bw2 = [Wlo | 0] ----
  bf16x8 bw1, bw2;
  float bav;
  {
    const int h = w8*16 + col;
    const float* wa = (w8 < 2) ? (w00a + h*16) : (w8 < 4) ? (w10a + (h-32)*16)
                    : (w8 < 6) ? (w01a + (h-64)*16) : (w11a + (h-96)*16);
    bav = (w8 < 2) ? b00a[h] : (w8 < 4) ? b10a[h-32] : (w8 < 6) ? b01a[h-64] : b11a[h-96];
    #pragma unroll
    for (int e = 0; e < 8; ++e) {
      HL s = splitbf(wa[(quad & 1)*8 + e]);
      bw1[e] = s.hi;
      bw2[e] = (quad < 2) ? s.lo : (short)0;
    }
  }

  // ---- per-lane LHS constants (wave-uniform branch selectors) ----
  int fdiv = 0, xrem = 0, cidx = 0;
  if (w8 >= 2 && w8 < 5) { const int idx = (w8-2)*16 + col; fdiv = idx/3; xrem = idx - 3*fdiv; }
  if (w8 >= 5) cidx = (w8-5)*16 + col;
  const int hb = (w8 == 0) ? 0 : (w8 == 1) ? 2 : (w8 < 5) ? 4 : 6;

  const int jrow = th >> 4, jfeat = th & 15;   // f0/rbf staging coords

  // ---- prefetch tile 0 of this half ----
  float pf_f0, pf_f1_0, pf_f1_1, pf_f1_2, pf_rh = 0.f, pf_rbf;
  int pf_mk = 0;
  {
    pf_f0   = f0[(jbase + jrow)*16 + jfeat];
    pf_f1_0 = f1[jbase*48 + th]; pf_f1_1 = f1[jbase*48 + th + 512]; pf_f1_2 = f1[jbase*48 + th + 1024];
    if (th < 96) pf_rh = rhat[((size_t)i*NTOK + jbase)*3 + th];
    if (th < 32) pf_mk = mask[(size_t)i*NTOK + jbase + th];
    pf_rbf  = rbf[((size_t)i*NTOK + jbase + jrow)*16 + jfeat];
  }

  f32x4 acc0 = {0.f,0.f,0.f,0.f}, acc1 = {0.f,0.f,0.f,0.f};
  float biasp = 0.f;
  const f32x4 zc = {0.f,0.f,0.f,0.f};

  for (int tile = 0; tile < NHALF; ++tile) {
    // ---- stage regs -> this half's LDS (f1: linear, index-register-free) ----
    smh->f0s[jrow*17 + jfeat] = pf_f0;
    smh->f1s[th]        = pf_f1_0;
    smh->f1s[th + 512]  = pf_f1_1;
    smh->f1s[th + 1024] = pf_f1_2;
    if (th < 96) smh->rhs[th] = pf_rh;
    if (th < 32) smh->maskf[th] = pf_mk ? 1.f : 0.f;
    { HL s = splitbf(pf_rbf);
      smh->rbfHL[jrow*40 + jfeat]      = s.hi;
      smh->rbfHL[jrow*40 + 16 + jfeat] = s.lo; }
    __syncthreads();   // staging visible (both halves in lockstep)

    // ---- prefetch tile+1 ----
    if (tile + 1 < NHALF) {
      const int j0 = jbase + (tile+1)*TJ;
      pf_f0   = f0[(j0 + jrow)*16 + jfeat];
      pf_f1_0 = f1[j0*48 + th]; pf_f1_1 = f1[j0*48 + th + 512]; pf_f1_2 = f1[j0*48 + th + 1024];
      if (th < 96) pf_rh = rhat[((size_t)i*NTOK + j0)*3 + th];
      if (th < 32) pf_mk = mask[(size_t)i*NTOK + j0 + th];
      pf_rbf  = rbf[((size_t)i*NTOK + j0 + jrow)*16 + jfeat];
    }

    // ---- phase A: H = silu(rbf @ WA^T + ba) ----
    {
      const bf16x8 a0 = *(const bf16x8*)&smh->rbfHL[col*40 + quad*8];
      const bf16x8 a1 = *(const bf16x8*)&smh->rbfHL[(16+col)*40 + quad*8];
      f32x4 d0 = __builtin_amdgcn_mfma_f32_16x16x32_bf16(a0, bw1, zc, 0, 0, 0);
      d0 = __builtin_amdgcn_mfma_f32_16x16x32_bf16(a0, bw2, d0, 0, 0, 0);
      f32x4 d1 = __builtin_amdgcn_mfma_f32_16x16x32_bf16(a1, bw1, zc, 0, 0, 0);
      d1 = __builtin_amdgcn_mfma_f32_16x16x32_bf16(a1, bw2, d1, 0, 0, 0);
      bf16x4 hv, lv;
      #pragma unroll
      for (int r = 0; r < 4; ++r) {
        float p = d0[r] + bav;
        float s = p * __builtin_amdgcn_rcpf(1.f + __expf(-p));
        HL e2 = splitbf(s); hv[r] = e2.hi; lv[r] = e2.lo;
      }
      *(bf16x4*)&smh->Hh[(w8*16+col)*40 + quad*4] = hv;
      *(bf16x4*)&smh->Hl[(w8*16+col)*40 + quad*4] = lv;
      #pragma unroll
      for (int r = 0; r < 4; ++r) {
        float p = d1[r] + bav;
        float s = p * __builtin_amdgcn_rcpf(1.f + __expf(-p));
        HL e2 = splitbf(s); hv[r] = e2.hi; lv[r] = e2.lo;
      }
      *(bf16x4*)&smh->Hh[(w8*16+col)*40 + 16 + quad*4] = hv;
      *(bf16x4*)&smh->Hl[(w8*16+col)*40 + 16 + quad*4] = lv;
    }

    // ---- LHS: STREAMED per-lane phase-B A-frag (R17-verbatim, stride 48) ----
    bf16x8 afh, afl;
    {
      const int jb = quad*8;
      #pragma unroll
      for (int jj = 0; jj < 8; ++jj) {
        const int j = jb + jj;
        const float mk = smh->maskf[j];
        float v;
        if (w8 == 0) {
          v = mk * smh->f0s[j*17 + col];
        } else if (w8 == 1) {
          const float* rp = &smh->rhs[j*3];
          const float* fr = &smh->f1s[j*48 + col*3];
          v = mk * (rp[0]*fr[0] + rp[1]*fr[1] + rp[2]*fr[2]);
        } else if (w8 < 5) {
          v = mk * smh->f0s[j*17 + fdiv] * smh->rhs[j*3 + xrem];
        } else {
          v = mk * smh->f1s[j*48 + cidx];
        }
        biasp += v;
        HL s = splitbf(v);
        afh[jj] = s.hi; afl[jj] = s.lo;
      }
    }
    __syncthreads();   // H visible; staging fully consumed

    // ---- phase B: ACC += L^T * H ----
    {
      const bf16x8 b0h = *(const bf16x8*)&smh->Hh[(hb*16+col)*40 + quad*8];
      const bf16x8 b0l = *(const bf16x8*)&smh->Hl[(hb*16+col)*40 + quad*8];
      const bf16x8 b1h = *(const bf16x8*)&smh->Hh[((hb+1)*16+col)*40 + quad*8];
      const bf16x8 b1l = *(const bf16x8*)&smh->Hl[((hb+1)*16+col)*40 + quad*8];
      acc0 = __builtin_amdgcn_mfma_f32_16x16x32_bf16(afl, b0h, acc0, 0, 0, 0);
      acc0 = __builtin_amdgcn_mfma_f32_16x16x32_bf16(afh, b0l, acc0, 0, 0, 0);
      acc0 = __builtin_amdgcn_mfma_f32_16x16x32_bf16(afh, b0h, acc0, 0, 0, 0);
      acc1 = __builtin_amdgcn_mfma_f32_16x16x32_bf16(afl, b1h, acc1, 0, 0, 0);
      acc1 = __builtin_amdgcn_mfma_f32_16x16x32_bf16(afh, b1l, acc1, 0, 0, 0);
      acc1 = __builtin_amdgcn_mfma_f32_16x16x32_bf16(afh, b1h, acc1, 0, 0, 0);
    }
  }

  __syncthreads();   // all main-loop LDS reads done -> union region reusable

  // ---- merge halves: half 0 writes, half 1 accumulates ----
  biasp += __shfl_xor(biasp, 16);
  biasp += __shfl_xor(biasp, 32);
  if (half == 0) {
    #pragma unroll
    for (int r = 0; r < 4; ++r) {
      sm.e.ACCs[(w8*16 + quad*4 + r)*33 + col]      = acc0[r];
      sm.e.ACCs[(w8*16 + quad*4 + r)*33 + 16 + col] = acc1[r];
    }
    if (lane < 16) sm.e.biasR[w8*16 + col] = biasp;
  }
  __syncthreads();
  if (half == 1) {
    #pragma unroll
    for (int r = 0; r < 4; ++r) {
      sm.e.ACCs[(w8*16 + quad*4 + r)*33 + col]      += acc0[r];
      sm.e.ACCs[(w8*16 + quad*4 + r)*33 + 16 + col] += acc1[r];
    }
    if (lane < 16) sm.e.biasR[w8*16 + col] += biasp;
  }
  __syncthreads();

  // ---- epilogue: second-layer contraction, 8-way split of the 16-long d loop ----
  {
    const int tt = t & 127, oct = t >> 7;   // oct 0..7
    float s = 0.f;
    if (tt < 16) {
      const int o = tt;
      #pragma unroll
      for (int dd = 0; dd < 2; ++dd) {
        const int d = oct + dd*8;
        const float* wrow = w00b + (d*16 + o)*32;
        float ss = 0.f;
        #pragma unroll
        for (int hh = 0; hh < 32; ++hh) ss += wrow[hh] * sm.e.ACCs[d*33 + hh];
        s += ss + b00b[d*16 + o] * sm.e.biasR[d];
      }
    } else if (tt < 32) {
      const int o = tt - 16;
      #pragma unroll
      for (int dd = 0; dd < 2; ++dd) {
        const int c = oct + dd*8, m = 16 + c;
        const float* wrow = w10b + (c*16 + o)*32;
        float ss = 0.f;
        #pragma unroll
        for (int hh = 0; hh < 32; ++hh) ss += wrow[hh] * sm.e.ACCs[m*33 + hh];
        s += ss + b10b[c*16 + o] * sm.e.biasR[m];
      }
    } else if (tt < 80) {
      const int idx = tt - 32, g = idx/3, x = idx - 3*g;
      #pragma unroll
      for (int dd = 0; dd < 2; ++dd) {
        const int f = oct + dd*8, m = 32 + f*3 + x;
        const float* wrow = w01b + (f*16 + g)*32;
        float ss = 0.f;
        #pragma unroll
        for (int hh = 0; hh < 32; ++hh) ss += wrow[hh] * sm.e.ACCs[m*33 + hh];
        s += ss + b01b[f*16 + g] * sm.e.biasR[m];
      }
    } else {
      const int idx = tt - 80, g = idx/3, x = idx - 3*g;
      #pragma unroll
      for (int dd = 0; dd < 2; ++dd) {
        const int k = oct + dd*8, m = 80 + k*3 + x;
        const float* wrow = w11b + (k*16 + g)*32;
        float ss = 0.f;
        #pragma unroll
        for (int hh = 0; hh < 32; ++hh) ss += wrow[hh] * sm.e.ACCs[m*33 + hh];
        s += ss + b11b[k*16 + g] * sm.e.biasR[m];
      }
    }
    sm.e.part[t] = s;
  }
  __syncthreads();

  if (t < 128) {
    float s = 0.f;
    #pragma unroll
    for (int k = 0; k < 8; ++k) s += sm.e.part[t + 128*k];
    if (t < 16) sm.e.m00s[t] = s;
    else if (t < 32) sm.e.m10s[t-16] = s;
    else if (t < 80) sm.e.p01s[t-32] = s;
    else sm.e.p11s[t-80] = s;
  }
  __syncthreads();

  if (t < 16) {
    float vv = sm.e.m00s[t] + sm.e.m10s[t];
    float mu = 0.f;
    #pragma unroll
    for (int k = 0; k < 16; ++k) mu += sm.e.m00s[k] + sm.e.m10s[k];
    mu *= (1.f/16.f);
    float var = 0.f;
    #pragma unroll
    for (int k = 0; k < 16; ++k) { float d = sm.e.m00s[k] + sm.e.m10s[k] - mu; var += d*d; }
    var *= (1.f/16.f);
    out[(size_t)i*16 + t] = (vv - mu) * rsqrtf(var + EPSF) * g0[t] + be0[t];
    float r0v = sm.e.p01s[t*3+0] + sm.e.p11s[t*3+0];
    float r1v = sm.e.p01s[t*3+1] + sm.e.p11s[t*3+1];
    float r2v = sm.e.p01s[t*3+2] + sm.e.p11s[t*3+2];
    sm.e.rawbs[t*3+0] = r0v; sm.e.rawbs[t*3+1] = r1v; sm.e.rawbs[t*3+2] = r2v;
    sm.e.nrms[t] = fmaxf(sqrtf(r0v*r0v + r1v*r1v + r2v*r2v), 1e-8f);
  }
  __syncthreads();
  if (t < 16) {
    float mu = 0.f;
    #pragma unroll
    for (int k = 0; k < 16; ++k) mu += sm.e.nrms[k];
    mu *= (1.f/16.f);
    float var = 0.f;
    #pragma unroll
    for (int k = 0; k < 16; ++k) { float d = sm.e.nrms[k] - mu; var += d*d; }
    var *= (1.f/16.f);
    const float ln = (sm.e.nrms[t] - mu) * rsqrtf(var + EPSF) * g1[t] + be1[t];
    const float scale = ln / sm.e.nrms[t];
    const size_t base = (size_t)NTOK*16 + (size_t)i*48 + t*3;
    out[base+0] = sm.e.rawbs[t*3+0] * scale;
    out[base+1] = sm.e.rawbs[t*3+1] * scale;
    out[base+2] = sm.e.rawbs[t*3+2] * scale;
  }
}

extern "C" void kernel_launch(void* const* d_in, const int* in_sizes, int n_in,
                              void* d_out, int out_size, void* d_ws, size_t ws_size,
                              hipStream_t stream) {
  int idx_f0 = -1, idx_f1 = -1, idx_rbf = -1, idx_rhat = -1, idx_mask = -1;
  int wa_i[4], ba_i[4], wb_i[4], bb_i[4], g_i[4];
  int nwa = 0, nba = 0, nwb = 0, nbb = 0, ng = 0;
  for (int k = 0; k < n_in; ++k) {
    const int s = in_sizes[k];
    if      (s == 4194304) idx_rbf  = k;
    else if (s == 786432)  idx_rhat = k;
    else if (s == 262144)  idx_mask = k;
    else if (s == 24576)   idx_f1   = k;
    else if (s == 8192)    { if (idx_f0 < 0) idx_f0 = k; else if (nwb < 4) wb_i[nwb++] = k; }
    else if (s == 512)     { if (nwa < 4) wa_i[nwa++] = k; }
    else if (s == 32)      { if (nba < 4) ba_i[nba++] = k; }
    else if (s == 256)     { if (nbb < 4) bb_i[nbb++] = k; }
    else if (s == 16)      { if (ng  < 4) g_i[ng++]  = k; }
  }
  const bool ok = idx_f0 >= 0 && idx_f1 >= 0 && idx_rbf >= 0 && idx_rhat >= 0 &&
                  idx_mask >= 0 && nwa == 4 && nba == 4 && nwb == 4 && nbb == 4 && ng == 4;
  if (!ok) {
    idx_f0 = 1; idx_f1 = 2; idx_rbf = 3; idx_rhat = 4; idx_mask = 5;
    for (int q = 0; q < 4; ++q) {
      wa_i[q] = 6 + q*4; ba_i[q] = 7 + q*4; wb_i[q] = 8 + q*4; bb_i[q] = 9 + q*4;
      g_i[q] = 22 + q;
    }
  }
  tfn_kernel<<<512, 1024, 0, stream>>>(
      (const float*)d_in[idx_f0],  (const float*)d_in[idx_f1],
      (const float*)d_in[idx_rbf], (const float*)d_in[idx_rhat],
      (const int*)d_in[idx_mask],
      (const float*)d_in[wa_i[0]], (const float*)d_in[ba_i[0]],
      (const float*)d_in[wb_i[0]], (const float*)d_in[bb_i[0]],
      (const float*)d_in[wa_i[1]], (const float*)d_in[ba_i[1]],
      (const float*)d_in[wb_i[1]], (const float*)d_in[bb_i[1]],
      (const float*)d_in[wa_i[2]], (const float*)d_in[ba_i[2]],
      (const float*)d_in[wb_i[2]], (const float*)d_in[bb_i[2]],
      (const float*)d_in[wa_i[3]], (const float*)d_in[ba_i[3]],
      (const float*)d_in[wb_i[3]], (const float*)d_in[bb_i[3]],
      (const float*)d_in[g_i[0]], (const float*)d_in[g_i[1]],
      (const float*)d_in[g_i[2]], (const float*)d_in[g_i[3]],
      (float*)d_out);
}